// Round 13
// baseline (624.755 us; speedup 1.0000x reference)
//
#include <hip/hip_runtime.h>
#include <hip/hip_bf16.h>

#define NN 100000     // nodes
#define NE 400000     // edges
#define DD 128        // feature dim
#define NG 4096       // graphs
#define NL 5          // layers
#define NF 11         // in features
#define GROWS 100096  // g rows rounded up (1564 gemm blocks * 64)

typedef __attribute__((ext_vector_type(8))) __bf16 bf16x8;
typedef __attribute__((ext_vector_type(4))) float f32x4;

// ---------------- preprocessing ----------------

__global__ void deg_kernel(const int* __restrict__ ei, int* __restrict__ deg) {
    int e = blockIdx.x * 256 + threadIdx.x;
    if (e < NE) atomicAdd(&deg[ei[NE + e]], 1);
}

// block scans 1024 elements (4 per thread), writes per-block total
__global__ void scan1_kernel(const int* __restrict__ deg, int* __restrict__ off,
                             int* __restrict__ bsums) {
    __shared__ int lds[256];
    int tid = threadIdx.x, b = blockIdx.x;
    int base = b * 1024 + tid * 4;
    int v[4];
#pragma unroll
    for (int q = 0; q < 4; ++q) {
        int i = base + q;
        v[q] = (i < NN) ? deg[i] : 0;
    }
    int s = v[0] + v[1] + v[2] + v[3];
    lds[tid] = s;
    __syncthreads();
    for (int o = 1; o < 256; o <<= 1) {
        int t2 = (tid >= o) ? lds[tid - o] : 0;
        __syncthreads();
        lds[tid] += t2;
        __syncthreads();
    }
    int p = lds[tid] - s;  // exclusive prefix for this thread
#pragma unroll
    for (int q = 0; q < 4; ++q) {
        int i = base + q;
        if (i < NN) off[i] = p;
        p += v[q];
    }
    if (tid == 255) bsums[b] = lds[255];
}

__global__ void scan2_kernel(int* __restrict__ bsums, int nb) {
    __shared__ int lds[128];
    int tid = threadIdx.x;
    int v = (tid < nb) ? bsums[tid] : 0;
    lds[tid] = v;
    __syncthreads();
    for (int o = 1; o < 128; o <<= 1) {
        int t2 = (tid >= o) ? lds[tid - o] : 0;
        __syncthreads();
        lds[tid] += t2;
        __syncthreads();
    }
    if (tid < nb) bsums[tid] = lds[tid] - v;  // exclusive
}

__global__ void finish_kernel(int* __restrict__ off, const int* __restrict__ bsums,
                              const int* __restrict__ deg, float* __restrict__ dinv) {
    int i = blockIdx.x * 256 + threadIdx.x;
    if (i < NN) {
        off[i] += bsums[i >> 10];
        dinv[i] = rsqrtf((float)deg[i] + 2.0f);
    }
}

// packed CSR record: .x = src index, .y = bitcast(norm)
// Allocates slots by atomically bumping off[d] itself: post-fill, off[d] equals the
// ORIGINAL exclusive-prefix off[d+1], so consumers use e0=(d?off[d-1]:0), e1=off[d].
__global__ void fill_kernel(const int* __restrict__ ei, int* __restrict__ off,
                            int2* __restrict__ csr, const float* __restrict__ dinv) {
    int e = blockIdx.x * 256 + threadIdx.x;
    if (e >= NE) return;
    int s = ei[e];
    int d = ei[NE + e];
    int pos = atomicAdd(&off[d], 1);
    csr[pos] = make_int2(s, __float_as_int(dinv[s] * dinv[d]));
}

// ---------------- W pre-pack: A-fragment-order bf16 hi/lo (W^T as MFMA A operand) ------
// Layout per layer: [ft(8)][kc(4)][lane(64)][i(8)]; slot (lane,i) holds
// A[row = ft*16 + (lane&15)][k = kc*32 + (lane>>4)*8 + i] = W[k][f].

__global__ void wpack_kernel(const float* __restrict__ Wg, unsigned short* __restrict__ whi,
                             unsigned short* __restrict__ wlo) {
    int t = blockIdx.x * 256 + threadIdx.x;  // < NL*16384
    int l = t >> 14, r = t & 16383;
    int k = r >> 7, n = r & 127;
    float w = Wg[(size_t)l * 16384 + k * 128 + n];
    __bf16 hb = (__bf16)w;
    float lo = w - (float)hb;
    __bf16 lb = (__bf16)lo;
    int ft = n >> 4, kc = k >> 5, lane = (((k >> 3) & 3) << 4) | (n & 15), i = k & 7;
    size_t idx = (size_t)l * 16384 + (((ft * 4 + kc) * 64 + lane) * 8 + i);
    whi[idx] = __builtin_bit_cast(unsigned short, hb);
    wlo[idx] = __builtin_bit_cast(unsigned short, lb);
}

// ---------------- expansion: h = log(x+1) @ We + be  (logs computed in-block) ----------

__global__ __launch_bounds__(256) void expand_kernel(const float* __restrict__ x,
                                                     const float* __restrict__ We,
                                                     const float* __restrict__ be,
                                                     float* __restrict__ h) {
    __shared__ float ls[2 * NF];
    const int tid = threadIdx.x;
    const int node0 = blockIdx.x * 2;
    if (tid < 2 * NF) ls[tid] = __logf(x[(size_t)node0 * NF + tid] + 1.0f);
    __syncthreads();
    const int row = tid >> 7, j = tid & 127;
    float acc = be[j];
#pragma unroll
    for (int f = 0; f < NF; ++f) {
        acc = fmaf(ls[row * NF + f], We[f * DD + j], acc);
    }
    h[(size_t)(node0 + row) * DD + j] = acc;
}

// ---------------- aggregation v6: 2 nodes per 32-lane group ----------------
// 8 independent 16B gathers in flight per thread (4 per node chain, predicated,
// clamped to valid csr memory; out-of-range weights zeroed). 16 nodes per block.
// OUTPUT: bf16 hi/lo directly in MFMA B-fragment order (same map as round 12):
//   thread(n, jj) owns k=jj*4+q: kc=jj>>3, kg=(jj>>1)&3, i0=(jj&1)*4,
//   lane'=(kg<<4)|(n&15); one 8B ushort4 store per buffer per node.

__device__ __forceinline__ void frag_store(unsigned short* __restrict__ gbh,
                                           unsigned short* __restrict__ gbl,
                                           int node, int jj, float4 acc) {
    __bf16 h0 = (__bf16)acc.x; __bf16 l0 = (__bf16)(acc.x - (float)h0);
    __bf16 h1 = (__bf16)acc.y; __bf16 l1 = (__bf16)(acc.y - (float)h1);
    __bf16 h2 = (__bf16)acc.z; __bf16 l2 = (__bf16)(acc.z - (float)h2);
    __bf16 h3 = (__bf16)acc.w; __bf16 l3 = (__bf16)(acc.w - (float)h3);
    const int tile = node >> 4;
    const int kc = jj >> 3;
    const int kg = (jj >> 1) & 3;
    const int i0 = (jj & 1) * 4;
    const int lanep = (kg << 4) | (node & 15);
    size_t base = (((size_t)tile * 4 + kc) * 64 + lanep) * 8 + i0;
    *(ushort4*)(gbh + base) = make_ushort4(__builtin_bit_cast(unsigned short, h0),
                                           __builtin_bit_cast(unsigned short, h1),
                                           __builtin_bit_cast(unsigned short, h2),
                                           __builtin_bit_cast(unsigned short, h3));
    *(ushort4*)(gbl + base) = make_ushort4(__builtin_bit_cast(unsigned short, l0),
                                           __builtin_bit_cast(unsigned short, l1),
                                           __builtin_bit_cast(unsigned short, l2),
                                           __builtin_bit_cast(unsigned short, l3));
}

__global__ __launch_bounds__(256) void agg_kernel(const float* __restrict__ h,
                                                  unsigned short* __restrict__ gbh,
                                                  unsigned short* __restrict__ gbl,
                                                  const int* __restrict__ off,
                                                  const int2* __restrict__ csr,
                                                  const float* __restrict__ dinv) {
    const int tid = threadIdx.x;
    const int grp = tid >> 5;
    const int jj = tid & 31;
    const int nodeA = blockIdx.x * 16 + grp * 2;
    const int nodeB = nodeA + 1;
    const float4* __restrict__ h4 = (const float4*)h;

    float diA = dinv[nodeA], diB = dinv[nodeB];
    float4 hvA = h4[(size_t)nodeA * 32 + jj];
    float4 hvB = h4[(size_t)nodeB * 32 + jj];
    float snA = 2.0f * diA * diA, snB = 2.0f * diB * diB;
    float4 aA = make_float4(snA * hvA.x, snA * hvA.y, snA * hvA.z, snA * hvA.w);
    float4 aB = make_float4(snB * hvB.x, snB * hvB.y, snB * hvB.z, snB * hvB.w);

    // off was mutated by fill: off[d] == original off[d+1]
    const int e0A = (nodeA == 0) ? 0 : off[nodeA - 1];
    const int e1A = off[nodeA];
    const int e1B = off[nodeB];
    int eA = e0A, eB = e1A;

#pragma unroll 1
    while (eA < e1A || eB < e1B) {
        int2 rA0 = csr[min(eA,     NE - 1)];
        int2 rA1 = csr[min(eA + 1, NE - 1)];
        int2 rA2 = csr[min(eA + 2, NE - 1)];
        int2 rA3 = csr[min(eA + 3, NE - 1)];
        int2 rB0 = csr[min(eB,     NE - 1)];
        int2 rB1 = csr[min(eB + 1, NE - 1)];
        int2 rB2 = csr[min(eB + 2, NE - 1)];
        int2 rB3 = csr[min(eB + 3, NE - 1)];
        float4 vA0 = h4[(size_t)rA0.x * 32 + jj];
        float4 vA1 = h4[(size_t)rA1.x * 32 + jj];
        float4 vA2 = h4[(size_t)rA2.x * 32 + jj];
        float4 vA3 = h4[(size_t)rA3.x * 32 + jj];
        float4 vB0 = h4[(size_t)rB0.x * 32 + jj];
        float4 vB1 = h4[(size_t)rB1.x * 32 + jj];
        float4 vB2 = h4[(size_t)rB2.x * 32 + jj];
        float4 vB3 = h4[(size_t)rB3.x * 32 + jj];
        float wA0 = (eA     < e1A) ? __int_as_float(rA0.y) : 0.f;
        float wA1 = (eA + 1 < e1A) ? __int_as_float(rA1.y) : 0.f;
        float wA2 = (eA + 2 < e1A) ? __int_as_float(rA2.y) : 0.f;
        float wA3 = (eA + 3 < e1A) ? __int_as_float(rA3.y) : 0.f;
        float wB0 = (eB     < e1B) ? __int_as_float(rB0.y) : 0.f;
        float wB1 = (eB + 1 < e1B) ? __int_as_float(rB1.y) : 0.f;
        float wB2 = (eB + 2 < e1B) ? __int_as_float(rB2.y) : 0.f;
        float wB3 = (eB + 3 < e1B) ? __int_as_float(rB3.y) : 0.f;
        aA.x = fmaf(wA0, vA0.x, aA.x); aA.y = fmaf(wA0, vA0.y, aA.y);
        aA.z = fmaf(wA0, vA0.z, aA.z); aA.w = fmaf(wA0, vA0.w, aA.w);
        aA.x = fmaf(wA1, vA1.x, aA.x); aA.y = fmaf(wA1, vA1.y, aA.y);
        aA.z = fmaf(wA1, vA1.z, aA.z); aA.w = fmaf(wA1, vA1.w, aA.w);
        aA.x = fmaf(wA2, vA2.x, aA.x); aA.y = fmaf(wA2, vA2.y, aA.y);
        aA.z = fmaf(wA2, vA2.z, aA.z); aA.w = fmaf(wA2, vA2.w, aA.w);
        aA.x = fmaf(wA3, vA3.x, aA.x); aA.y = fmaf(wA3, vA3.y, aA.y);
        aA.z = fmaf(wA3, vA3.z, aA.z); aA.w = fmaf(wA3, vA3.w, aA.w);
        aB.x = fmaf(wB0, vB0.x, aB.x); aB.y = fmaf(wB0, vB0.y, aB.y);
        aB.z = fmaf(wB0, vB0.z, aB.z); aB.w = fmaf(wB0, vB0.w, aB.w);
        aB.x = fmaf(wB1, vB1.x, aB.x); aB.y = fmaf(wB1, vB1.y, aB.y);
        aB.z = fmaf(wB1, vB1.z, aB.z); aB.w = fmaf(wB1, vB1.w, aB.w);
        aB.x = fmaf(wB2, vB2.x, aB.x); aB.y = fmaf(wB2, vB2.y, aB.y);
        aB.z = fmaf(wB2, vB2.z, aB.z); aB.w = fmaf(wB2, vB2.w, aB.w);
        aB.x = fmaf(wB3, vB3.x, aB.x); aB.y = fmaf(wB3, vB3.y, aB.y);
        aB.z = fmaf(wB3, vB3.z, aB.z); aB.w = fmaf(wB3, vB3.w, aB.w);
        eA += 4;
        eB += 4;
    }

    frag_store(gbh, gbl, nodeA, jj, aA);
    frag_store(gbh, gbl, nodeB, jj, aB);
}

// ---------------- MFMA GEMM v5 (pre-packed g fragments): D = W^T · g^T ----------------
// h[n][:] += relu((g@W)[n][:] + b).  No LDS, no barriers, no conversions.
// Wave = 16 nodes x 128 features; block = 4 waves = 64 nodes.
// 3-term split: Whi*ghi + Wlo*ghi + Whi*glo (fp32 accum).
// C/D fragment: col=lane&15 -> node, row=(lane>>4)*4+j -> 4 consecutive features.

__global__ __launch_bounds__(256) void mfma_gemm(const unsigned short* __restrict__ gbh,
                                                 const unsigned short* __restrict__ gbl,
                                                 float* __restrict__ h,
                                                 const unsigned short* __restrict__ whi,
                                                 const unsigned short* __restrict__ wlo,
                                                 const float* __restrict__ b) {
    const int lane = threadIdx.x & 63;
    const int wv = threadIdx.x >> 6;
    const int nbase = blockIdx.x * 64 + wv * 16;
    const size_t tbase = ((size_t)(nbase >> 4) * 4 * 64 + lane) * 8;

    bf16x8 gh[4], gl[4];
#pragma unroll
    for (int kc = 0; kc < 4; ++kc) {
        gh[kc] = *(const bf16x8*)(gbh + tbase + kc * 512);
        gl[kc] = *(const bf16x8*)(gbl + tbase + kc * 512);
    }

    f32x4 c[8];
#pragma unroll
    for (int ft = 0; ft < 8; ++ft) c[ft] = (f32x4){0.f, 0.f, 0.f, 0.f};

#pragma unroll
    for (int kc = 0; kc < 4; ++kc) {
#pragma unroll
        for (int ft = 0; ft < 8; ++ft) {
            size_t boff = (size_t)(((ft * 4 + kc) * 64 + lane) * 8);
            bf16x8 wh = *(const bf16x8*)(whi + boff);
            bf16x8 wl = *(const bf16x8*)(wlo + boff);
            c[ft] = __builtin_amdgcn_mfma_f32_16x16x32_bf16(wh, gh[kc], c[ft], 0, 0, 0);
            c[ft] = __builtin_amdgcn_mfma_f32_16x16x32_bf16(wl, gh[kc], c[ft], 0, 0, 0);
            c[ft] = __builtin_amdgcn_mfma_f32_16x16x32_bf16(wh, gl[kc], c[ft], 0, 0, 0);
        }
    }

    const int node = nbase + (lane & 15);
    const int f0 = (lane >> 4) * 4;
    if (node < NN) {
#pragma unroll
        for (int ft = 0; ft < 8; ++ft) {
            size_t o = (size_t)node * DD + ft * 16 + f0;
            float4 hv = *(const float4*)(h + o);
            float4 bv = *(const float4*)(b + ft * 16 + f0);
            hv.x += fmaxf(c[ft][0] + bv.x, 0.f);
            hv.y += fmaxf(c[ft][1] + bv.y, 0.f);
            hv.z += fmaxf(c[ft][2] + bv.z, 0.f);
            hv.w += fmaxf(c[ft][3] + bv.w, 0.f);
            *(float4*)(h + o) = hv;
        }
    }
}

// ---------------- pool: out[batch[i]] += h[i]  (batch sorted) ----------------

__global__ void pool_kernel(const float* __restrict__ h, const int* __restrict__ batch,
                            float* __restrict__ out) {
    int j = threadIdx.x;  // 128
    int n0 = blockIdx.x * 64;
    float acc = 0.f;
    int prev = -1;
    for (int n = 0; n < 64; ++n) {
        int i = n0 + n;
        if (i >= NN) break;
        int bi = batch[i];
        if (bi != prev) {
            if (prev >= 0) atomicAdd(&out[(size_t)prev * DD + j], acc);
            acc = 0.f;
            prev = bi;
        }
        acc += h[(size_t)i * DD + j];
    }
    if (prev >= 0) atomicAdd(&out[(size_t)prev * DD + j], acc);
}

// ---------------- launch ----------------

static inline size_t align_up(size_t x, size_t a) { return (x + a - 1) & ~(a - 1); }

extern "C" void kernel_launch(void* const* d_in, const int* in_sizes, int n_in,
                              void* d_out, int out_size, void* d_ws, size_t ws_size,
                              hipStream_t stream) {
    const float* x   = (const float*)d_in[0];
    const int*   ei  = (const int*)d_in[1];
    const int*   bat = (const int*)d_in[2];
    const float* We  = (const float*)d_in[4];
    const float* be  = (const float*)d_in[5];
    const float* Wg  = (const float*)d_in[6];
    const float* bg  = (const float*)d_in[7];
    float* out = (float*)d_out;

    // workspace carve-up
    char* p = (char*)d_ws;
    size_t o = 0;
    float* h = (float*)(p + o);       o = align_up(o + (size_t)NN * DD * 4, 512);
    unsigned short* gbh = (unsigned short*)(p + o); o = align_up(o + (size_t)GROWS * DD * 2, 512);
    unsigned short* gbl = (unsigned short*)(p + o); o = align_up(o + (size_t)GROWS * DD * 2, 512);
    float* dinv = (float*)(p + o);    o = align_up(o + (size_t)NN * 4, 512);
    int* deg = (int*)(p + o);         o = align_up(o + (size_t)NN * 4, 512);
    int* off = (int*)(p + o);         o = align_up(o + (size_t)(NN + 1) * 4, 512);
    int* bsums = (int*)(p + o);       o = align_up(o + 512, 512);
    int2* csr = (int2*)(p + o);       o = align_up(o + (size_t)NE * 8, 512);
    unsigned short* whi = (unsigned short*)(p + o); o = align_up(o + (size_t)NL * 16384 * 2, 512);
    unsigned short* wlo = (unsigned short*)(p + o); o = align_up(o + (size_t)NL * 16384 * 2, 512);
    (void)ws_size; (void)in_sizes; (void)n_in; (void)out_size;

    const int GRID_E = (NE + 255) / 256;          // 1563
    const int GRID_SCAN1 = (NN + 1023) / 1024;    // 98
    const int GRID_N256 = (NN + 255) / 256;       // 391
    const int GRID_EXP = NN / 2;                  // 50000
    const int GRID_AGG = NN / 16;                 // 6250
    const int GRID_GEMM = GROWS / 64;             // 1564
    const int GRID_POOL = (NN + 63) / 64;         // 1563
    const int GRID_WPACK = NL * 16384 / 256;      // 320

    // zero deg (ws is poisoned 0xAA each call); out must be zeroed for pool atomics
    hipMemsetAsync(deg, 0, (size_t)NN * 4, stream);
    hipMemsetAsync(out, 0, (size_t)NG * DD * 4, stream);

    deg_kernel<<<GRID_E, 256, 0, stream>>>(ei, deg);
    scan1_kernel<<<GRID_SCAN1, 256, 0, stream>>>(deg, off, bsums);
    scan2_kernel<<<1, 128, 0, stream>>>(bsums, GRID_SCAN1);
    finish_kernel<<<GRID_N256, 256, 0, stream>>>(off, bsums, deg, dinv);
    fill_kernel<<<GRID_E, 256, 0, stream>>>(ei, off, csr, dinv);
    wpack_kernel<<<GRID_WPACK, 256, 0, stream>>>(Wg, whi, wlo);

    expand_kernel<<<GRID_EXP, 256, 0, stream>>>(x, We, be, h);

    for (int l = 0; l < NL; ++l) {
        agg_kernel<<<GRID_AGG, 256, 0, stream>>>(h, gbh, gbl, off, csr, dinv);
        mfma_gemm<<<GRID_GEMM, 256, 0, stream>>>(gbh, gbl, h,
                                                 whi + (size_t)l * 16384,
                                                 wlo + (size_t)l * 16384,
                                                 bg + (size_t)l * DD);
    }

    pool_kernel<<<GRID_POOL, 128, 0, stream>>>(h, bat, out);
}

// Round 14
// 581.800 us; speedup vs baseline: 1.0738x; 1.0738x over previous
//
#include <hip/hip_runtime.h>
#include <hip/hip_bf16.h>

#define NN 100000     // nodes
#define NE 400000     // edges
#define DD 128        // feature dim
#define NG 4096       // graphs
#define NL 5          // layers
#define NF 11         // in features
#define GROWS 100096  // g rows rounded up (782 gemm blocks * 128)

typedef __attribute__((ext_vector_type(8))) __bf16 bf16x8;
typedef __attribute__((ext_vector_type(4))) float f32x4;

// ---------------- preprocessing ----------------

__global__ void deg_kernel(const int* __restrict__ ei, int* __restrict__ deg) {
    int e = blockIdx.x * 256 + threadIdx.x;
    if (e < NE) atomicAdd(&deg[ei[NE + e]], 1);
}

// block scans 1024 elements (4 per thread), writes per-block total
__global__ void scan1_kernel(const int* __restrict__ deg, int* __restrict__ off,
                             int* __restrict__ bsums) {
    __shared__ int lds[256];
    int tid = threadIdx.x, b = blockIdx.x;
    int base = b * 1024 + tid * 4;
    int v[4];
#pragma unroll
    for (int q = 0; q < 4; ++q) {
        int i = base + q;
        v[q] = (i < NN) ? deg[i] : 0;
    }
    int s = v[0] + v[1] + v[2] + v[3];
    lds[tid] = s;
    __syncthreads();
    for (int o = 1; o < 256; o <<= 1) {
        int t2 = (tid >= o) ? lds[tid - o] : 0;
        __syncthreads();
        lds[tid] += t2;
        __syncthreads();
    }
    int p = lds[tid] - s;  // exclusive prefix for this thread
#pragma unroll
    for (int q = 0; q < 4; ++q) {
        int i = base + q;
        if (i < NN) off[i] = p;
        p += v[q];
    }
    if (tid == 255) bsums[b] = lds[255];
}

__global__ void scan2_kernel(int* __restrict__ bsums, int nb) {
    __shared__ int lds[128];
    int tid = threadIdx.x;
    int v = (tid < nb) ? bsums[tid] : 0;
    lds[tid] = v;
    __syncthreads();
    for (int o = 1; o < 128; o <<= 1) {
        int t2 = (tid >= o) ? lds[tid - o] : 0;
        __syncthreads();
        lds[tid] += t2;
        __syncthreads();
    }
    if (tid < nb) bsums[tid] = lds[tid] - v;  // exclusive
}

__global__ void finish_kernel(int* __restrict__ off, const int* __restrict__ bsums,
                              const int* __restrict__ deg, float* __restrict__ dinv) {
    int i = blockIdx.x * 256 + threadIdx.x;
    if (i < NN) {
        off[i] += bsums[i >> 10];
        dinv[i] = rsqrtf((float)deg[i] + 2.0f);
    }
}

// packed CSR record: .x = src index, .y = bitcast(norm)
// Allocates slots by atomically bumping off[d]: post-fill, off[d] equals the
// ORIGINAL exclusive-prefix off[d+1]; consumers use e0=(d?off[d-1]:0), e1=off[d].
__global__ void fill_kernel(const int* __restrict__ ei, int* __restrict__ off,
                            int2* __restrict__ csr, const float* __restrict__ dinv) {
    int e = blockIdx.x * 256 + threadIdx.x;
    if (e >= NE) return;
    int s = ei[e];
    int d = ei[NE + e];
    int pos = atomicAdd(&off[d], 1);
    csr[pos] = make_int2(s, __float_as_int(dinv[s] * dinv[d]));
}

// ---------------- W pre-pack: A-fragment-order bf16 hi/lo (W^T as MFMA A operand) ------
// Layout per layer: [ft(8)][kc(4)][lane(64)][i(8)]; slot (lane,i) holds
// A[row = ft*16 + (lane&15)][k = kc*32 + (lane>>4)*8 + i] = W[k][f].

__global__ void wpack_kernel(const float* __restrict__ Wg, unsigned short* __restrict__ whi,
                             unsigned short* __restrict__ wlo) {
    int t = blockIdx.x * 256 + threadIdx.x;  // < NL*16384
    int l = t >> 14, r = t & 16383;
    int k = r >> 7, n = r & 127;
    float w = Wg[(size_t)l * 16384 + k * 128 + n];
    __bf16 hb = (__bf16)w;
    float lo = w - (float)hb;
    __bf16 lb = (__bf16)lo;
    int ft = n >> 4, kc = k >> 5, lane = (((k >> 3) & 3) << 4) | (n & 15), i = k & 7;
    size_t idx = (size_t)l * 16384 + (((ft * 4 + kc) * 64 + lane) * 8 + i);
    whi[idx] = __builtin_bit_cast(unsigned short, hb);
    wlo[idx] = __builtin_bit_cast(unsigned short, lb);
}

// ---------------- expansion: h = log(x+1) @ We + be  (8 nodes/block) ----------------
// 88 logs staged in LDS; each thread owns one column j and 4 nodes -> We reused x4.

__global__ __launch_bounds__(256) void expand_kernel(const float* __restrict__ x,
                                                     const float* __restrict__ We,
                                                     const float* __restrict__ be,
                                                     float* __restrict__ h) {
    __shared__ float ls[8 * NF];
    const int tid = threadIdx.x;
    const int node0 = blockIdx.x * 8;
    if (tid < 8 * NF) ls[tid] = __logf(x[(size_t)node0 * NF + tid] + 1.0f);
    __syncthreads();
    const int j = tid & 127;
    float wv[NF], acc0 = be[j];
#pragma unroll
    for (int f = 0; f < NF; ++f) wv[f] = We[f * DD + j];
#pragma unroll
    for (int r = 0; r < 4; ++r) {
        const int nl = r * 2 + (tid >> 7);
        float acc = acc0;
#pragma unroll
        for (int f = 0; f < NF; ++f) acc = fmaf(ls[nl * NF + f], wv[f], acc);
        h[(size_t)(node0 + nl) * DD + j] = acc;
    }
}

// ---------------- aggregation (round-12 proven): 1 node per 32-lane group ------------
// Predicated 4-unroll: 4 independent 16B gathers in flight; clamp only within the
// node's own edge range (no cross-chain waste). OUTPUT: bf16 hi/lo in MFMA
// B-fragment order: thread(n, jj) owns k=jj*4+q -> kc=jj>>3, kg=(jj>>1)&3,
// i0=(jj&1)*4, lane'=(kg<<4)|(n&15); one 8B ushort4 store per buffer.

__global__ __launch_bounds__(256) void agg_kernel(const float* __restrict__ h,
                                                  unsigned short* __restrict__ gbh,
                                                  unsigned short* __restrict__ gbl,
                                                  const int* __restrict__ off,
                                                  const int2* __restrict__ csr,
                                                  const float* __restrict__ dinv) {
    const int tid = threadIdx.x;
    const int node = blockIdx.x * 8 + (tid >> 5);
    const int jj = tid & 31;
    const float4* __restrict__ h4 = (const float4*)h;

    float di = dinv[node];
    float sn = 2.0f * di * di;
    float4 hv = h4[(size_t)node * 32 + jj];
    float4 acc = make_float4(sn * hv.x, sn * hv.y, sn * hv.z, sn * hv.w);

    // off was mutated by fill: off[d] == original off[d+1]
    const int e0 = (node == 0) ? 0 : off[node - 1];
    const int e1 = off[node];
#pragma unroll 1
    for (int e = e0; e < e1; e += 4) {
        const int eL = e1 - 1;
        int2 r0 = csr[e];
        int2 r1 = csr[min(e + 1, eL)];
        int2 r2 = csr[min(e + 2, eL)];
        int2 r3 = csr[min(e + 3, eL)];
        float4 v0 = h4[(size_t)r0.x * 32 + jj];
        float4 v1 = h4[(size_t)r1.x * 32 + jj];
        float4 v2 = h4[(size_t)r2.x * 32 + jj];
        float4 v3 = h4[(size_t)r3.x * 32 + jj];
        float w0 = __int_as_float(r0.y);
        float w1 = (e + 1 < e1) ? __int_as_float(r1.y) : 0.f;
        float w2 = (e + 2 < e1) ? __int_as_float(r2.y) : 0.f;
        float w3 = (e + 3 < e1) ? __int_as_float(r3.y) : 0.f;
        acc.x = fmaf(w0, v0.x, acc.x); acc.y = fmaf(w0, v0.y, acc.y);
        acc.z = fmaf(w0, v0.z, acc.z); acc.w = fmaf(w0, v0.w, acc.w);
        acc.x = fmaf(w1, v1.x, acc.x); acc.y = fmaf(w1, v1.y, acc.y);
        acc.z = fmaf(w1, v1.z, acc.z); acc.w = fmaf(w1, v1.w, acc.w);
        acc.x = fmaf(w2, v2.x, acc.x); acc.y = fmaf(w2, v2.y, acc.y);
        acc.z = fmaf(w2, v2.z, acc.z); acc.w = fmaf(w2, v2.w, acc.w);
        acc.x = fmaf(w3, v3.x, acc.x); acc.y = fmaf(w3, v3.y, acc.y);
        acc.z = fmaf(w3, v3.z, acc.z); acc.w = fmaf(w3, v3.w, acc.w);
    }

    // split + fragment-order store
    __bf16 h0 = (__bf16)acc.x; __bf16 l0 = (__bf16)(acc.x - (float)h0);
    __bf16 h1 = (__bf16)acc.y; __bf16 l1 = (__bf16)(acc.y - (float)h1);
    __bf16 h2 = (__bf16)acc.z; __bf16 l2 = (__bf16)(acc.z - (float)h2);
    __bf16 h3 = (__bf16)acc.w; __bf16 l3 = (__bf16)(acc.w - (float)h3);
    const int tile = node >> 4;
    const int kc = jj >> 3;
    const int kg = (jj >> 1) & 3;
    const int i0 = (jj & 1) * 4;
    const int lanep = (kg << 4) | (node & 15);
    size_t base = (((size_t)tile * 4 + kc) * 64 + lanep) * 8 + i0;
    *(ushort4*)(gbh + base) = make_ushort4(__builtin_bit_cast(unsigned short, h0),
                                           __builtin_bit_cast(unsigned short, h1),
                                           __builtin_bit_cast(unsigned short, h2),
                                           __builtin_bit_cast(unsigned short, h3));
    *(ushort4*)(gbl + base) = make_ushort4(__builtin_bit_cast(unsigned short, l0),
                                           __builtin_bit_cast(unsigned short, l1),
                                           __builtin_bit_cast(unsigned short, l2),
                                           __builtin_bit_cast(unsigned short, l3));
}

// ---------------- MFMA GEMM v6 (packed g, 2 node-tiles/wave): D = W^T · g^T ----------
// Each W fragment feeds TWO node-tiles -> W L2 traffic halves, 6 MFMA per 2 W-loads.
// Wave = 32 nodes x 128 features; block = 4 waves = 128 nodes. No LDS, no barriers.
// g fragment loads are lane-contiguous 16B (16 independent, in flight together).
// 3-term split: Whi*ghi + Wlo*ghi + Whi*glo (fp32 accum).
// C/D fragment: col=lane&15 -> node, row=(lane>>4)*4+j -> 4 consecutive features.

__global__ __launch_bounds__(256) void mfma_gemm(const unsigned short* __restrict__ gbh,
                                                 const unsigned short* __restrict__ gbl,
                                                 float* __restrict__ h,
                                                 const unsigned short* __restrict__ whi,
                                                 const unsigned short* __restrict__ wlo,
                                                 const float* __restrict__ b) {
    const int lane = threadIdx.x & 63;
    const int wv = threadIdx.x >> 6;
    const int nbase = blockIdx.x * 128 + wv * 32;
    const size_t tbase = ((size_t)(nbase >> 4) * 4 * 64 + lane) * 8;  // tile stride 2048

    bf16x8 gh[2][4], gl[2][4];
#pragma unroll
    for (int nt = 0; nt < 2; ++nt)
#pragma unroll
        for (int kc = 0; kc < 4; ++kc) {
            gh[nt][kc] = *(const bf16x8*)(gbh + tbase + nt * 2048 + kc * 512);
            gl[nt][kc] = *(const bf16x8*)(gbl + tbase + nt * 2048 + kc * 512);
        }

    f32x4 c[2][8];
#pragma unroll
    for (int nt = 0; nt < 2; ++nt)
#pragma unroll
        for (int ft = 0; ft < 8; ++ft) c[nt][ft] = (f32x4){0.f, 0.f, 0.f, 0.f};

#pragma unroll
    for (int kc = 0; kc < 4; ++kc) {
#pragma unroll
        for (int ft = 0; ft < 8; ++ft) {
            size_t boff = (size_t)(((ft * 4 + kc) * 64 + lane) * 8);
            bf16x8 wh = *(const bf16x8*)(whi + boff);
            bf16x8 wl = *(const bf16x8*)(wlo + boff);
#pragma unroll
            for (int nt = 0; nt < 2; ++nt) {
                c[nt][ft] = __builtin_amdgcn_mfma_f32_16x16x32_bf16(wh, gh[nt][kc], c[nt][ft], 0, 0, 0);
                c[nt][ft] = __builtin_amdgcn_mfma_f32_16x16x32_bf16(wl, gh[nt][kc], c[nt][ft], 0, 0, 0);
                c[nt][ft] = __builtin_amdgcn_mfma_f32_16x16x32_bf16(wh, gl[nt][kc], c[nt][ft], 0, 0, 0);
            }
        }
    }

    const int f0 = (lane >> 4) * 4;
#pragma unroll
    for (int nt = 0; nt < 2; ++nt) {
        const int node = nbase + nt * 16 + (lane & 15);
        if (node < NN) {
#pragma unroll
            for (int ft = 0; ft < 8; ++ft) {
                size_t o = (size_t)node * DD + ft * 16 + f0;
                float4 hv = *(const float4*)(h + o);
                float4 bv = *(const float4*)(b + ft * 16 + f0);
                hv.x += fmaxf(c[nt][ft][0] + bv.x, 0.f);
                hv.y += fmaxf(c[nt][ft][1] + bv.y, 0.f);
                hv.z += fmaxf(c[nt][ft][2] + bv.z, 0.f);
                hv.w += fmaxf(c[nt][ft][3] + bv.w, 0.f);
                *(float4*)(h + o) = hv;
            }
        }
    }
}

// ---------------- pool: out[batch[i]] += h[i]  (batch sorted) ----------------

__global__ void pool_kernel(const float* __restrict__ h, const int* __restrict__ batch,
                            float* __restrict__ out) {
    int j = threadIdx.x;  // 128
    int n0 = blockIdx.x * 64;
    float acc = 0.f;
    int prev = -1;
    for (int n = 0; n < 64; ++n) {
        int i = n0 + n;
        if (i >= NN) break;
        int bi = batch[i];
        if (bi != prev) {
            if (prev >= 0) atomicAdd(&out[(size_t)prev * DD + j], acc);
            acc = 0.f;
            prev = bi;
        }
        acc += h[(size_t)i * DD + j];
    }
    if (prev >= 0) atomicAdd(&out[(size_t)prev * DD + j], acc);
}

// ---------------- launch ----------------

static inline size_t align_up(size_t x, size_t a) { return (x + a - 1) & ~(a - 1); }

extern "C" void kernel_launch(void* const* d_in, const int* in_sizes, int n_in,
                              void* d_out, int out_size, void* d_ws, size_t ws_size,
                              hipStream_t stream) {
    const float* x   = (const float*)d_in[0];
    const int*   ei  = (const int*)d_in[1];
    const int*   bat = (const int*)d_in[2];
    const float* We  = (const float*)d_in[4];
    const float* be  = (const float*)d_in[5];
    const float* Wg  = (const float*)d_in[6];
    const float* bg  = (const float*)d_in[7];
    float* out = (float*)d_out;

    // workspace carve-up
    char* p = (char*)d_ws;
    size_t o = 0;
    float* h = (float*)(p + o);       o = align_up(o + (size_t)NN * DD * 4, 512);
    unsigned short* gbh = (unsigned short*)(p + o); o = align_up(o + (size_t)GROWS * DD * 2, 512);
    unsigned short* gbl = (unsigned short*)(p + o); o = align_up(o + (size_t)GROWS * DD * 2, 512);
    float* dinv = (float*)(p + o);    o = align_up(o + (size_t)NN * 4, 512);
    int* deg = (int*)(p + o);         o = align_up(o + (size_t)NN * 4, 512);
    int* off = (int*)(p + o);         o = align_up(o + (size_t)(NN + 1) * 4, 512);
    int* bsums = (int*)(p + o);       o = align_up(o + 512, 512);
    int2* csr = (int2*)(p + o);       o = align_up(o + (size_t)NE * 8, 512);
    unsigned short* whi = (unsigned short*)(p + o); o = align_up(o + (size_t)NL * 16384 * 2, 512);
    unsigned short* wlo = (unsigned short*)(p + o); o = align_up(o + (size_t)NL * 16384 * 2, 512);
    (void)ws_size; (void)in_sizes; (void)n_in; (void)out_size;

    const int GRID_E = (NE + 255) / 256;          // 1563
    const int GRID_SCAN1 = (NN + 1023) / 1024;    // 98
    const int GRID_N256 = (NN + 255) / 256;       // 391
    const int GRID_EXP = NN / 8;                  // 12500
    const int GRID_AGG = NN / 8;                  // 12500
    const int GRID_GEMM = GROWS / 128;            // 782
    const int GRID_POOL = (NN + 63) / 64;         // 1563
    const int GRID_WPACK = NL * 16384 / 256;      // 320

    // zero deg (ws is poisoned 0xAA each call); out must be zeroed for pool atomics
    hipMemsetAsync(deg, 0, (size_t)NN * 4, stream);
    hipMemsetAsync(out, 0, (size_t)NG * DD * 4, stream);

    deg_kernel<<<GRID_E, 256, 0, stream>>>(ei, deg);
    scan1_kernel<<<GRID_SCAN1, 256, 0, stream>>>(deg, off, bsums);
    scan2_kernel<<<1, 128, 0, stream>>>(bsums, GRID_SCAN1);
    finish_kernel<<<GRID_N256, 256, 0, stream>>>(off, bsums, deg, dinv);
    fill_kernel<<<GRID_E, 256, 0, stream>>>(ei, off, csr, dinv);
    wpack_kernel<<<GRID_WPACK, 256, 0, stream>>>(Wg, whi, wlo);

    expand_kernel<<<GRID_EXP, 256, 0, stream>>>(x, We, be, h);

    for (int l = 0; l < NL; ++l) {
        agg_kernel<<<GRID_AGG, 256, 0, stream>>>(h, gbh, gbl, off, csr, dinv);
        mfma_gemm<<<GRID_GEMM, 256, 0, stream>>>(gbh, gbl, h,
                                                 whi + (size_t)l * 16384,
                                                 wlo + (size_t)l * 16384,
                                                 bg + (size_t)l * DD);
    }

    pool_kernel<<<GRID_POOL, 128, 0, stream>>>(h, bat, out);
}

// Round 15
// 540.930 us; speedup vs baseline: 1.1550x; 1.0756x over previous
//
#include <hip/hip_runtime.h>
#include <hip/hip_bf16.h>

#define NN 100000     // nodes
#define NE 400000     // edges
#define DD 128        // feature dim
#define NG 4096       // graphs
#define NL 5          // layers
#define NF 11         // in features
#define GROWS 100096  // g rows rounded up (782 gemm blocks * 128)

typedef __attribute__((ext_vector_type(8))) __bf16 bf16x8;
typedef __attribute__((ext_vector_type(4))) float f32x4;

// ---------------- preprocessing ----------------

__global__ void deg_kernel(const int* __restrict__ ei, int* __restrict__ deg) {
    int e = blockIdx.x * 256 + threadIdx.x;
    if (e < NE) atomicAdd(&deg[ei[NE + e]], 1);
}

// block scans 1024 elements (4 per thread), writes per-block total
__global__ void scan1_kernel(const int* __restrict__ deg, int* __restrict__ off,
                             int* __restrict__ bsums) {
    __shared__ int lds[256];
    int tid = threadIdx.x, b = blockIdx.x;
    int base = b * 1024 + tid * 4;
    int v[4];
#pragma unroll
    for (int q = 0; q < 4; ++q) {
        int i = base + q;
        v[q] = (i < NN) ? deg[i] : 0;
    }
    int s = v[0] + v[1] + v[2] + v[3];
    lds[tid] = s;
    __syncthreads();
    for (int o = 1; o < 256; o <<= 1) {
        int t2 = (tid >= o) ? lds[tid - o] : 0;
        __syncthreads();
        lds[tid] += t2;
        __syncthreads();
    }
    int p = lds[tid] - s;  // exclusive prefix for this thread
#pragma unroll
    for (int q = 0; q < 4; ++q) {
        int i = base + q;
        if (i < NN) off[i] = p;
        p += v[q];
    }
    if (tid == 255) bsums[b] = lds[255];
}

__global__ void scan2_kernel(int* __restrict__ bsums, int nb) {
    __shared__ int lds[128];
    int tid = threadIdx.x;
    int v = (tid < nb) ? bsums[tid] : 0;
    lds[tid] = v;
    __syncthreads();
    for (int o = 1; o < 128; o <<= 1) {
        int t2 = (tid >= o) ? lds[tid - o] : 0;
        __syncthreads();
        lds[tid] += t2;
        __syncthreads();
    }
    if (tid < nb) bsums[tid] = lds[tid] - v;  // exclusive
}

__global__ void finish_kernel(int* __restrict__ off, const int* __restrict__ bsums,
                              const int* __restrict__ deg, float* __restrict__ dinv) {
    int i = blockIdx.x * 256 + threadIdx.x;
    if (i < NN) {
        off[i] += bsums[i >> 10];
        dinv[i] = rsqrtf((float)deg[i] + 2.0f);
    }
}

// packed CSR record: .x = src index, .y = bitcast(norm)
// Allocates slots by atomically bumping off[d]: post-fill, off[d] equals the
// ORIGINAL exclusive-prefix off[d+1]; consumers use e0=(d?off[d-1]:0), e1=off[d].
__global__ void fill_kernel(const int* __restrict__ ei, int* __restrict__ off,
                            int2* __restrict__ csr, const float* __restrict__ dinv) {
    int e = blockIdx.x * 256 + threadIdx.x;
    if (e >= NE) return;
    int s = ei[e];
    int d = ei[NE + e];
    int pos = atomicAdd(&off[d], 1);
    csr[pos] = make_int2(s, __float_as_int(dinv[s] * dinv[d]));
}

// ---------------- W pre-pack: A-fragment-order bf16 hi/lo (W^T as MFMA A operand) ------
// Layout per layer: [ft(8)][kc(4)][lane(64)][i(8)]; slot (lane,i) holds
// A[row = ft*16 + (lane&15)][k = kc*32 + (lane>>4)*8 + i] = W[k][f].

__global__ void wpack_kernel(const float* __restrict__ Wg, unsigned short* __restrict__ whi,
                             unsigned short* __restrict__ wlo) {
    int t = blockIdx.x * 256 + threadIdx.x;  // < NL*16384
    int l = t >> 14, r = t & 16383;
    int k = r >> 7, n = r & 127;
    float w = Wg[(size_t)l * 16384 + k * 128 + n];
    __bf16 hb = (__bf16)w;
    float lo = w - (float)hb;
    __bf16 lb = (__bf16)lo;
    int ft = n >> 4, kc = k >> 5, lane = (((k >> 3) & 3) << 4) | (n & 15), i = k & 7;
    size_t idx = (size_t)l * 16384 + (((ft * 4 + kc) * 64 + lane) * 8 + i);
    whi[idx] = __builtin_bit_cast(unsigned short, hb);
    wlo[idx] = __builtin_bit_cast(unsigned short, lb);
}

// ---------------- expansion: h = log(x+1) @ We + be  (8 nodes/block) ----------------

__global__ __launch_bounds__(256) void expand_kernel(const float* __restrict__ x,
                                                     const float* __restrict__ We,
                                                     const float* __restrict__ be,
                                                     float* __restrict__ h) {
    __shared__ float ls[8 * NF];
    const int tid = threadIdx.x;
    const int node0 = blockIdx.x * 8;
    if (tid < 8 * NF) ls[tid] = __logf(x[(size_t)node0 * NF + tid] + 1.0f);
    __syncthreads();
    const int j = tid & 127;
    float wv[NF], acc0 = be[j];
#pragma unroll
    for (int f = 0; f < NF; ++f) wv[f] = We[f * DD + j];
#pragma unroll
    for (int r = 0; r < 4; ++r) {
        const int nl = r * 2 + (tid >> 7);
        float acc = acc0;
#pragma unroll
        for (int f = 0; f < NF; ++f) acc = fmaf(ls[nl * NF + f], wv[f], acc);
        h[(size_t)(node0 + nl) * DD + j] = acc;
    }
}

// ---------------- aggregation (proven): 1 node per 32-lane group ------------
// Predicated 4-unroll: 4 independent 16B gathers in flight; clamped dup loads are
// same-row L1 hits. OUTPUT: bf16 hi/lo in MFMA B-fragment order: thread(n, jj)
// owns k=jj*4+q -> kc=jj>>3, kg=(jj>>1)&3, i0=(jj&1)*4, lane'=(kg<<4)|(n&15).

__global__ __launch_bounds__(256) void agg_kernel(const float* __restrict__ h,
                                                  unsigned short* __restrict__ gbh,
                                                  unsigned short* __restrict__ gbl,
                                                  const int* __restrict__ off,
                                                  const int2* __restrict__ csr,
                                                  const float* __restrict__ dinv) {
    const int tid = threadIdx.x;
    const int node = blockIdx.x * 8 + (tid >> 5);
    const int jj = tid & 31;
    const float4* __restrict__ h4 = (const float4*)h;

    float di = dinv[node];
    float sn = 2.0f * di * di;
    float4 hv = h4[(size_t)node * 32 + jj];
    float4 acc = make_float4(sn * hv.x, sn * hv.y, sn * hv.z, sn * hv.w);

    // off was mutated by fill: off[d] == original off[d+1]
    const int e0 = (node == 0) ? 0 : off[node - 1];
    const int e1 = off[node];
#pragma unroll 1
    for (int e = e0; e < e1; e += 4) {
        const int eL = e1 - 1;
        int2 r0 = csr[e];
        int2 r1 = csr[min(e + 1, eL)];
        int2 r2 = csr[min(e + 2, eL)];
        int2 r3 = csr[min(e + 3, eL)];
        float4 v0 = h4[(size_t)r0.x * 32 + jj];
        float4 v1 = h4[(size_t)r1.x * 32 + jj];
        float4 v2 = h4[(size_t)r2.x * 32 + jj];
        float4 v3 = h4[(size_t)r3.x * 32 + jj];
        float w0 = __int_as_float(r0.y);
        float w1 = (e + 1 < e1) ? __int_as_float(r1.y) : 0.f;
        float w2 = (e + 2 < e1) ? __int_as_float(r2.y) : 0.f;
        float w3 = (e + 3 < e1) ? __int_as_float(r3.y) : 0.f;
        acc.x = fmaf(w0, v0.x, acc.x); acc.y = fmaf(w0, v0.y, acc.y);
        acc.z = fmaf(w0, v0.z, acc.z); acc.w = fmaf(w0, v0.w, acc.w);
        acc.x = fmaf(w1, v1.x, acc.x); acc.y = fmaf(w1, v1.y, acc.y);
        acc.z = fmaf(w1, v1.z, acc.z); acc.w = fmaf(w1, v1.w, acc.w);
        acc.x = fmaf(w2, v2.x, acc.x); acc.y = fmaf(w2, v2.y, acc.y);
        acc.z = fmaf(w2, v2.z, acc.z); acc.w = fmaf(w2, v2.w, acc.w);
        acc.x = fmaf(w3, v3.x, acc.x); acc.y = fmaf(w3, v3.y, acc.y);
        acc.z = fmaf(w3, v3.z, acc.z); acc.w = fmaf(w3, v3.w, acc.w);
    }

    // split + fragment-order store
    __bf16 h0 = (__bf16)acc.x; __bf16 l0 = (__bf16)(acc.x - (float)h0);
    __bf16 h1 = (__bf16)acc.y; __bf16 l1 = (__bf16)(acc.y - (float)h1);
    __bf16 h2 = (__bf16)acc.z; __bf16 l2 = (__bf16)(acc.z - (float)h2);
    __bf16 h3 = (__bf16)acc.w; __bf16 l3 = (__bf16)(acc.w - (float)h3);
    const int tile = node >> 4;
    const int kc = jj >> 3;
    const int kg = (jj >> 1) & 3;
    const int i0 = (jj & 1) * 4;
    const int lanep = (kg << 4) | (node & 15);
    size_t base = (((size_t)tile * 4 + kc) * 64 + lanep) * 8 + i0;
    *(ushort4*)(gbh + base) = make_ushort4(__builtin_bit_cast(unsigned short, h0),
                                           __builtin_bit_cast(unsigned short, h1),
                                           __builtin_bit_cast(unsigned short, h2),
                                           __builtin_bit_cast(unsigned short, h3));
    *(ushort4*)(gbl + base) = make_ushort4(__builtin_bit_cast(unsigned short, l0),
                                           __builtin_bit_cast(unsigned short, l1),
                                           __builtin_bit_cast(unsigned short, l2),
                                           __builtin_bit_cast(unsigned short, l3));
}

// ---------------- MFMA GEMM v7 (W staged in LDS, 2 node-tiles/wave) ----------------
// Block stages the ENTIRE packed W (hi+lo = 64KB) into LDS with one coalesced pass;
// g fragment loads issued first so they fly under the staging. One barrier, then
// waves run free: fragments via ds_read_b128 (lane-contiguous, conflict-free).
// W global traffic per block: 64KB (was 256KB). LDS 64KB -> 2 blocks/CU (8 waves).
// 3-term split: Whi*ghi + Wlo*ghi + Whi*glo (fp32 accum).
// C/D fragment: col=lane&15 -> node, row=(lane>>4)*4+j -> 4 consecutive features.

__global__ __launch_bounds__(256) void mfma_gemm(const unsigned short* __restrict__ gbh,
                                                 const unsigned short* __restrict__ gbl,
                                                 float* __restrict__ h,
                                                 const unsigned short* __restrict__ whi,
                                                 const unsigned short* __restrict__ wlo,
                                                 const float* __restrict__ b) {
    __shared__ __align__(16) unsigned short ws0[16384];
    __shared__ __align__(16) unsigned short ws1[16384];
    const int tid = threadIdx.x;
    const int lane = tid & 63;
    const int wv = tid >> 6;
    const int nbase = blockIdx.x * 128 + wv * 32;
    const size_t tbase = ((size_t)(nbase >> 4) * 4 * 64 + lane) * 8;  // tile stride 2048

    // g fragment loads first (16 independent 16B, fly under W staging)
    bf16x8 gh[2][4], gl[2][4];
#pragma unroll
    for (int nt = 0; nt < 2; ++nt)
#pragma unroll
        for (int kc = 0; kc < 4; ++kc) {
            gh[nt][kc] = *(const bf16x8*)(gbh + tbase + nt * 2048 + kc * 512);
            gl[nt][kc] = *(const bf16x8*)(gbl + tbase + nt * 2048 + kc * 512);
        }

    // cooperative W stage: 16384 ushorts per buffer, 8 ushorts (16B) per thread per iter
#pragma unroll
    for (int it = 0; it < 8; ++it) {
        int o = it * 2048 + tid * 8;
        *(int4*)(ws0 + o) = *(const int4*)(whi + o);
        *(int4*)(ws1 + o) = *(const int4*)(wlo + o);
    }
    __syncthreads();

    f32x4 c[2][8];
#pragma unroll
    for (int nt = 0; nt < 2; ++nt)
#pragma unroll
        for (int ft = 0; ft < 8; ++ft) c[nt][ft] = (f32x4){0.f, 0.f, 0.f, 0.f};

#pragma unroll
    for (int kc = 0; kc < 4; ++kc) {
#pragma unroll
        for (int ft = 0; ft < 8; ++ft) {
            const int boff = ((ft * 4 + kc) * 64 + lane) * 8;
            bf16x8 wh = *(const bf16x8*)(ws0 + boff);
            bf16x8 wl = *(const bf16x8*)(ws1 + boff);
#pragma unroll
            for (int nt = 0; nt < 2; ++nt) {
                c[nt][ft] = __builtin_amdgcn_mfma_f32_16x16x32_bf16(wh, gh[nt][kc], c[nt][ft], 0, 0, 0);
                c[nt][ft] = __builtin_amdgcn_mfma_f32_16x16x32_bf16(wl, gh[nt][kc], c[nt][ft], 0, 0, 0);
                c[nt][ft] = __builtin_amdgcn_mfma_f32_16x16x32_bf16(wh, gl[nt][kc], c[nt][ft], 0, 0, 0);
            }
        }
    }

    const int f0 = (lane >> 4) * 4;
#pragma unroll
    for (int nt = 0; nt < 2; ++nt) {
        const int node = nbase + nt * 16 + (lane & 15);
        if (node < NN) {
#pragma unroll
            for (int ft = 0; ft < 8; ++ft) {
                size_t o = (size_t)node * DD + ft * 16 + f0;
                float4 hv = *(const float4*)(h + o);
                float4 bv = *(const float4*)(b + ft * 16 + f0);
                hv.x += fmaxf(c[nt][ft][0] + bv.x, 0.f);
                hv.y += fmaxf(c[nt][ft][1] + bv.y, 0.f);
                hv.z += fmaxf(c[nt][ft][2] + bv.z, 0.f);
                hv.w += fmaxf(c[nt][ft][3] + bv.w, 0.f);
                *(float4*)(h + o) = hv;
            }
        }
    }
}

// ---------------- pool v2: out[batch[i]] += h[i]  (batch sorted) ----------------
// 512 threads = 4 groups of 128; each group accumulates a 16-node run.

__global__ __launch_bounds__(512) void pool_kernel(const float* __restrict__ h,
                                                   const int* __restrict__ batch,
                                                   float* __restrict__ out) {
    const int j = threadIdx.x & 127;
    const int gg = threadIdx.x >> 7;  // 0..3
    const int n0 = blockIdx.x * 64 + gg * 16;
    float acc = 0.f;
    int prev = -1;
    for (int n = 0; n < 16; ++n) {
        int i = n0 + n;
        if (i >= NN) break;
        int bi = batch[i];
        if (bi != prev) {
            if (prev >= 0) atomicAdd(&out[(size_t)prev * DD + j], acc);
            acc = 0.f;
            prev = bi;
        }
        acc += h[(size_t)i * DD + j];
    }
    if (prev >= 0) atomicAdd(&out[(size_t)prev * DD + j], acc);
}

// ---------------- launch ----------------

static inline size_t align_up(size_t x, size_t a) { return (x + a - 1) & ~(a - 1); }

extern "C" void kernel_launch(void* const* d_in, const int* in_sizes, int n_in,
                              void* d_out, int out_size, void* d_ws, size_t ws_size,
                              hipStream_t stream) {
    const float* x   = (const float*)d_in[0];
    const int*   ei  = (const int*)d_in[1];
    const int*   bat = (const int*)d_in[2];
    const float* We  = (const float*)d_in[4];
    const float* be  = (const float*)d_in[5];
    const float* Wg  = (const float*)d_in[6];
    const float* bg  = (const float*)d_in[7];
    float* out = (float*)d_out;

    // workspace carve-up
    char* p = (char*)d_ws;
    size_t o = 0;
    float* h = (float*)(p + o);       o = align_up(o + (size_t)NN * DD * 4, 512);
    unsigned short* gbh = (unsigned short*)(p + o); o = align_up(o + (size_t)GROWS * DD * 2, 512);
    unsigned short* gbl = (unsigned short*)(p + o); o = align_up(o + (size_t)GROWS * DD * 2, 512);
    float* dinv = (float*)(p + o);    o = align_up(o + (size_t)NN * 4, 512);
    int* deg = (int*)(p + o);         o = align_up(o + (size_t)NN * 4, 512);
    int* off = (int*)(p + o);         o = align_up(o + (size_t)(NN + 1) * 4, 512);
    int* bsums = (int*)(p + o);       o = align_up(o + 512, 512);
    int2* csr = (int2*)(p + o);       o = align_up(o + (size_t)NE * 8, 512);
    unsigned short* whi = (unsigned short*)(p + o); o = align_up(o + (size_t)NL * 16384 * 2, 512);
    unsigned short* wlo = (unsigned short*)(p + o); o = align_up(o + (size_t)NL * 16384 * 2, 512);
    (void)ws_size; (void)in_sizes; (void)n_in; (void)out_size;

    const int GRID_E = (NE + 255) / 256;          // 1563
    const int GRID_SCAN1 = (NN + 1023) / 1024;    // 98
    const int GRID_N256 = (NN + 255) / 256;       // 391
    const int GRID_EXP = NN / 8;                  // 12500
    const int GRID_AGG = NN / 8;                  // 12500
    const int GRID_GEMM = GROWS / 128;            // 782
    const int GRID_POOL = (NN + 63) / 64;         // 1563
    const int GRID_WPACK = NL * 16384 / 256;      // 320

    // zero deg (ws is poisoned 0xAA each call); out must be zeroed for pool atomics
    hipMemsetAsync(deg, 0, (size_t)NN * 4, stream);
    hipMemsetAsync(out, 0, (size_t)NG * DD * 4, stream);

    deg_kernel<<<GRID_E, 256, 0, stream>>>(ei, deg);
    scan1_kernel<<<GRID_SCAN1, 256, 0, stream>>>(deg, off, bsums);
    scan2_kernel<<<1, 128, 0, stream>>>(bsums, GRID_SCAN1);
    finish_kernel<<<GRID_N256, 256, 0, stream>>>(off, bsums, deg, dinv);
    fill_kernel<<<GRID_E, 256, 0, stream>>>(ei, off, csr, dinv);
    wpack_kernel<<<GRID_WPACK, 256, 0, stream>>>(Wg, whi, wlo);

    expand_kernel<<<GRID_EXP, 256, 0, stream>>>(x, We, be, h);

    for (int l = 0; l < NL; ++l) {
        agg_kernel<<<GRID_AGG, 256, 0, stream>>>(h, gbh, gbl, off, csr, dinv);
        mfma_gemm<<<GRID_GEMM, 256, 0, stream>>>(gbh, gbl, h,
                                                 whi + (size_t)l * 16384,
                                                 wlo + (size_t)l * 16384,
                                                 bg + (size_t)l * DD);
    }

    pool_kernel<<<GRID_POOL, 512, 0, stream>>>(h, bat, out);
}